// Round 3
// baseline (671.204 us; speedup 1.0000x reference)
//
#include <hip/hip_runtime.h>

// Problem is fixed-shape: B=8192, N=4096, M=4096, G=512, CB=256.
#define B_DIM 8192
#define N_DIM 4096
#define M_DIM 4096
#define G_DIM 512

typedef short bf16x8 __attribute__((ext_vector_type(8)));
typedef float f32x4 __attribute__((ext_vector_type(4)));

__device__ __forceinline__ unsigned short f2bf(float f) {
    union { float f; unsigned int u; } v; v.f = f;
    unsigned int u = v.u;
    unsigned int r = (u + 0x7fffu + ((u >> 16) & 1u)) >> 16;
    return (unsigned short)r;
}

// In-register H16 (unnormalized Hadamard over 16 values).
__device__ __forceinline__ void h16(float* v) {
#pragma unroll
    for (int h = 1; h < 16; h <<= 1) {
#pragma unroll
        for (int i = 0; i < 16; i++) {
            if (!(i & h)) {
                float a = v[i], b = v[i | h];
                v[i] = a + b;
                v[i | h] = a - b;
            }
        }
    }
}

// ---------------------------------------------------------------------------
// Kernel 1: W[m][g*8+j] = (cb1[q1[m][g]][j] + cb2[q2[m][g]][j]*irs) * Wscale
// Output bf16 (internal GEMM operand only).
// ---------------------------------------------------------------------------
__global__ __launch_bounds__(256) void k_build_w(
    const int* __restrict__ q1, const int* __restrict__ q2,
    const float* __restrict__ cb1, const float* __restrict__ cb2,
    const float* __restrict__ wsp, const float* __restrict__ irsp,
    unsigned short* __restrict__ W) {
    __shared__ float c1[256 * 9];
    __shared__ float c2[256 * 9];
    int t = threadIdx.x;
#pragma unroll
    for (int j = 0; j < 8; j++) {
        c1[t * 9 + j] = cb1[t * 8 + j];
        c2[t * 9 + j] = cb2[t * 8 + j];
    }
    __syncthreads();
    float ws = wsp[0];
    float irs = irsp[0] * ws;
    int gid = blockIdx.x * 256 + t;  // exact multiple, no guard needed
    int i1 = q1[gid] * 9;
    int i2 = q2[gid] * 9;
    union { unsigned short s[8]; int4 v; } o;
#pragma unroll
    for (int j = 0; j < 8; j++) {
        o.s[j] = f2bf(c1[i1 + j] * ws + c2[i2 + j] * irs);
    }
    *(int4*)(W + (size_t)gid * 8) = o.v;
}

// ---------------------------------------------------------------------------
// Kernel 2: x_rht = fht(x * SV) -> bf16 (internal GEMM operand).
// One block (256 thr) per row of 4096. H4096 = H16 x H16 x H16 over
// bit-groups, padded-LDS shuffles between. 1/64 normalization folded in.
// ---------------------------------------------------------------------------
__global__ __launch_bounds__(256) void k_rht_in(
    const float* __restrict__ x, const float* __restrict__ SV,
    unsigned short* __restrict__ out) {
    __shared__ float lds[4352];  // f(n) = n + (n>>4), max 4350
    int row = blockIdx.x;
    int t = threadIdx.x;
    const float* xr = x + (size_t)row * N_DIM;
    float v[16];
    // phase A: n = t + 256r
#pragma unroll
    for (int r = 0; r < 16; r++) {
        int n = t + (r << 8);
        v[r] = xr[n] * SV[n] * 0.015625f;
    }
    h16(v);
#pragma unroll
    for (int r = 0; r < 16; r++) { int n = t + (r << 8); lds[n + (n >> 4)] = v[r]; }
    __syncthreads();
    // phase B: n = 16t + r
#pragma unroll
    for (int r = 0; r < 16; r++) { int n = (t << 4) + r; v[r] = lds[n + (n >> 4)]; }
    h16(v);
#pragma unroll
    for (int r = 0; r < 16; r++) { int n = (t << 4) + r; lds[n + (n >> 4)] = v[r]; }
    __syncthreads();
    // phase C: n = (t&15) | (r<<4) | ((t>>4)<<8)
#pragma unroll
    for (int r = 0; r < 16; r++) {
        int n = (t & 15) | (r << 4) | ((t >> 4) << 8);
        v[r] = lds[n + (n >> 4)];
    }
    h16(v);
#pragma unroll
    for (int r = 0; r < 16; r++) {
        int n = (t & 15) | (r << 4) | ((t >> 4) << 8);
        lds[n + (n >> 4)] = v[r];
    }
    __syncthreads();
    unsigned short* orow = out + (size_t)row * N_DIM;
#pragma unroll
    for (int r = 0; r < 16; r++) {
        int n = t + (r << 8);
        orow[n] = f2bf(lds[n + (n >> 4)]);
    }
}

// ---------------------------------------------------------------------------
// Kernel 3: y_rht = x_rht @ W^T  (NT GEMM, both row-major with K inner).
// 128x128x32 tile, 4 waves x (4x4 of 16x16x32 bf16 MFMA), int4 staging.
// OUTPUT IS FLOAT32 into d_out (reference output dtype is f32).
// ---------------------------------------------------------------------------
__global__ __launch_bounds__(256) void k_gemm(
    const unsigned short* __restrict__ A,   // (B_DIM, N_DIM) bf16
    const unsigned short* __restrict__ Bw,  // (M_DIM, N_DIM) bf16
    float* __restrict__ C) {                // (B_DIM, M_DIM) f32
    __shared__ __align__(16) unsigned short As[128 * 32];
    __shared__ __align__(16) unsigned short Bs[128 * 32];
    int t = threadIdx.x;
    int w = t >> 6;
    int l = t & 63;
    int bn = blockIdx.x;  // M tile
    int bm = blockIdx.y;  // B tile

    // staging: 512 16B-chunks per tile (128 rows x 4 chunks), 2 per thread
    int c0 = t;
    int c1 = t + 256;
    int r0 = c0 >> 2, k0 = (c0 & 3) * 8;
    int r1 = c1 >> 2, k1 = (c1 & 3) * 8;
    const unsigned short* gA0 = A + (size_t)(bm * 128 + r0) * N_DIM + k0;
    const unsigned short* gA1 = A + (size_t)(bm * 128 + r1) * N_DIM + k1;
    const unsigned short* gB0 = Bw + (size_t)(bn * 128 + r0) * N_DIM + k0;
    const unsigned short* gB1 = Bw + (size_t)(bn * 128 + r1) * N_DIM + k1;
    int4* sA0 = (int4*)As + c0;
    int4* sA1 = (int4*)As + c1;
    int4* sB0 = (int4*)Bs + c0;
    int4* sB1 = (int4*)Bs + c1;

    int wm = (w & 1) << 6;  // wave quadrant
    int wn = (w >> 1) << 6;
    int quad = l >> 4;
    int ln = l & 15;

    // MFMA fragment pointers: A[m=lane&15][k=quad*8+j]  (m91-verified layout)
    const unsigned short* arp[4];
    const unsigned short* brp[4];
#pragma unroll
    for (int i = 0; i < 4; i++) arp[i] = &As[(wm + i * 16 + ln) * 32 + quad * 8];
#pragma unroll
    for (int j = 0; j < 4; j++) brp[j] = &Bs[(wn + j * 16 + ln) * 32 + quad * 8];

    f32x4 acc[4][4];
#pragma unroll
    for (int i = 0; i < 4; i++)
#pragma unroll
        for (int j = 0; j < 4; j++) {
            f32x4 z = {0.f, 0.f, 0.f, 0.f};
            acc[i][j] = z;
        }

    for (int kk = 0; kk < N_DIM / 32; kk++) {
        int4 a0 = *(const int4*)gA0;
        int4 a1 = *(const int4*)gA1;
        int4 b0 = *(const int4*)gB0;
        int4 b1 = *(const int4*)gB1;
        gA0 += 32; gA1 += 32; gB0 += 32; gB1 += 32;
        *sA0 = a0; *sA1 = a1; *sB0 = b0; *sB1 = b1;
        __syncthreads();
        bf16x8 af[4], bfr[4];
#pragma unroll
        for (int i = 0; i < 4; i++) af[i] = *(const bf16x8*)arp[i];
#pragma unroll
        for (int j = 0; j < 4; j++) bfr[j] = *(const bf16x8*)brp[j];
#pragma unroll
        for (int i = 0; i < 4; i++)
#pragma unroll
            for (int j = 0; j < 4; j++)
                acc[i][j] = __builtin_amdgcn_mfma_f32_16x16x32_bf16(
                    af[i], bfr[j], acc[i][j], 0, 0, 0);
        __syncthreads();
    }

    // epilogue: C/D layout col=lane&15, row=quad*4+reg  (m89/m91-verified)
#pragma unroll
    for (int i = 0; i < 4; i++) {
#pragma unroll
        for (int j = 0; j < 4; j++) {
            int col = bn * 128 + wn + j * 16 + ln;
#pragma unroll
            for (int r = 0; r < 4; r++) {
                int rowg = bm * 128 + wm + i * 16 + quad * 4 + r;
                C[(size_t)rowg * M_DIM + col] = acc[i][j][r];
            }
        }
    }
}

// ---------------------------------------------------------------------------
// Kernel 4: y = fht(y_rht) * SU, in place on d_out (FLOAT32).
// ---------------------------------------------------------------------------
__global__ __launch_bounds__(256) void k_rht_out(
    float* __restrict__ y, const float* __restrict__ SU) {
    __shared__ float lds[4352];
    int row = blockIdx.x;
    int t = threadIdx.x;
    float* yr = y + (size_t)row * M_DIM;
    float v[16];
#pragma unroll
    for (int r = 0; r < 16; r++) {
        int n = t + (r << 8);
        v[r] = yr[n];
    }
    h16(v);
#pragma unroll
    for (int r = 0; r < 16; r++) { int n = t + (r << 8); lds[n + (n >> 4)] = v[r]; }
    __syncthreads();
#pragma unroll
    for (int r = 0; r < 16; r++) { int n = (t << 4) + r; v[r] = lds[n + (n >> 4)]; }
    h16(v);
#pragma unroll
    for (int r = 0; r < 16; r++) { int n = (t << 4) + r; lds[n + (n >> 4)] = v[r]; }
    __syncthreads();
#pragma unroll
    for (int r = 0; r < 16; r++) {
        int n = (t & 15) | (r << 4) | ((t >> 4) << 8);
        v[r] = lds[n + (n >> 4)];
    }
    h16(v);
#pragma unroll
    for (int r = 0; r < 16; r++) {
        int n = (t & 15) | (r << 4) | ((t >> 4) << 8);
        lds[n + (n >> 4)] = v[r];
    }
    __syncthreads();
#pragma unroll
    for (int r = 0; r < 16; r++) {
        int n = t + (r << 8);
        yr[n] = lds[n + (n >> 4)] * 0.015625f * SU[n];
    }
}

extern "C" void kernel_launch(void* const* d_in, const int* in_sizes, int n_in,
                              void* d_out, int out_size, void* d_ws, size_t ws_size,
                              hipStream_t stream) {
    const float* x    = (const float*)d_in[0];
    const int*   q1   = (const int*)d_in[1];
    const int*   q2   = (const int*)d_in[2];
    const float* SU   = (const float*)d_in[3];
    const float* SV   = (const float*)d_in[4];
    const float* cb1  = (const float*)d_in[5];
    const float* cb2  = (const float*)d_in[6];
    const float* wsp  = (const float*)d_in[7];
    const float* irsp = (const float*)d_in[8];
    float* out = (float*)d_out;  // reference output dtype: float32

    // workspace: x_rht bf16 (64MiB) | W bf16 (32MiB)  => 96MiB total
    unsigned short* xrht = (unsigned short*)d_ws;
    unsigned short* Wb   = xrht + (size_t)B_DIM * N_DIM;

    k_build_w<<<dim3((M_DIM * G_DIM) / 256), dim3(256), 0, stream>>>(
        q1, q2, cb1, cb2, wsp, irsp, Wb);
    k_rht_in<<<dim3(B_DIM), dim3(256), 0, stream>>>(x, SV, xrht);
    k_gemm<<<dim3(M_DIM / 128, B_DIM / 128), dim3(256), 0, stream>>>(xrht, Wb, out);
    k_rht_out<<<dim3(B_DIM), dim3(256), 0, stream>>>(out, SU);
}

// Round 4
// 605.677 us; speedup vs baseline: 1.1082x; 1.1082x over previous
//
#include <hip/hip_runtime.h>

// Problem is fixed-shape: B=8192, N=4096, M=4096, G=512, CB=256.
#define B_DIM 8192
#define N_DIM 4096
#define M_DIM 4096
#define G_DIM 512

typedef short bf16x8 __attribute__((ext_vector_type(8)));
typedef float f32x4 __attribute__((ext_vector_type(4)));

typedef __attribute__((address_space(1))) const void gvoid_t;
typedef __attribute__((address_space(3))) void lvoid_t;

__device__ __forceinline__ void load_lds16(const void* g, void* l) {
    __builtin_amdgcn_global_load_lds((gvoid_t*)g, (lvoid_t*)l, 16, 0, 0);
}

__device__ __forceinline__ unsigned short f2bf(float f) {
    union { float f; unsigned int u; } v; v.f = f;
    unsigned int u = v.u;
    unsigned int r = (u + 0x7fffu + ((u >> 16) & 1u)) >> 16;
    return (unsigned short)r;
}
__device__ __forceinline__ float bf2f(unsigned short s) {
    union { unsigned int u; float f; } v; v.u = ((unsigned int)s) << 16;
    return v.f;
}

// In-register H16 (unnormalized Hadamard over 16 values).
__device__ __forceinline__ void h16(float* v) {
#pragma unroll
    for (int h = 1; h < 16; h <<= 1) {
#pragma unroll
        for (int i = 0; i < 16; i++) {
            if (!(i & h)) {
                float a = v[i], b = v[i | h];
                v[i] = a + b;
                v[i | h] = a - b;
            }
        }
    }
}

// In-register H64 (unnormalized Hadamard over 64 values).
__device__ __forceinline__ void h64(float* v) {
#pragma unroll
    for (int h = 1; h < 64; h <<= 1) {
#pragma unroll
        for (int i = 0; i < 64; i++) {
            if (!(i & h)) {
                float a = v[i], b = v[i | h];
                v[i] = a + b;
                v[i | h] = a - b;
            }
        }
    }
}

// ---------------------------------------------------------------------------
// Kernel 1: W[m][g*8+j] = (cb1[q1[m][g]][j] + cb2[q2[m][g]][j]*irs) * Wscale
// Output bf16 (internal GEMM operand only).
// ---------------------------------------------------------------------------
__global__ __launch_bounds__(256) void k_build_w(
    const int* __restrict__ q1, const int* __restrict__ q2,
    const float* __restrict__ cb1, const float* __restrict__ cb2,
    const float* __restrict__ wsp, const float* __restrict__ irsp,
    unsigned short* __restrict__ W) {
    __shared__ float c1[256 * 9];
    __shared__ float c2[256 * 9];
    int t = threadIdx.x;
#pragma unroll
    for (int j = 0; j < 8; j++) {
        c1[t * 9 + j] = cb1[t * 8 + j];
        c2[t * 9 + j] = cb2[t * 8 + j];
    }
    __syncthreads();
    float ws = wsp[0];
    float irs = irsp[0] * ws;
    int gid = blockIdx.x * 256 + t;  // exact multiple, no guard needed
    int i1 = q1[gid] * 9;
    int i2 = q2[gid] * 9;
    union { unsigned short s[8]; int4 v; } o;
#pragma unroll
    for (int j = 0; j < 8; j++) {
        o.s[j] = f2bf(c1[i1 + j] * ws + c2[i2 + j] * irs);
    }
    *(int4*)(W + (size_t)gid * 8) = o.v;
}

// ---------------------------------------------------------------------------
// Kernel 1b: column-direction Hadamard on W (in place, bf16).
// W'' = (1/64) * H_4096 applied over the row index m of W[m][c].
// H_4096 = H_64(hi bits of m) (x) H_64(lo bits). Two passes:
//   pass1: base_mul=1,  step=64, scale=1        (transform over hi)
//   pass2: base_mul=64, step=1,  scale=1/64     (transform over lo)
// Thread t of block (bx,by) owns column c=bx*256+t, chain by.
// Disjoint row/col ownership per block -> in-place safe.
// ---------------------------------------------------------------------------
__global__ __launch_bounds__(256) void k_hadw(
    unsigned short* __restrict__ W, int base_mul, int step, float scale) {
    int c = blockIdx.x * 256 + threadIdx.x;
    int base = blockIdx.y * base_mul;
    float v[64];
#pragma unroll
    for (int j = 0; j < 64; j++)
        v[j] = bf2f(W[(size_t)(base + j * step) * N_DIM + c]);
    h64(v);
#pragma unroll
    for (int j = 0; j < 64; j++)
        W[(size_t)(base + j * step) * N_DIM + c] = f2bf(v[j] * scale);
}

// ---------------------------------------------------------------------------
// Kernel 2: x_rht = fht(x * SV) -> bf16 (internal GEMM operand).
// One block (256 thr) per row of 4096. H4096 = H16 x H16 x H16 over
// bit-groups, padded-LDS shuffles between. 1/64 normalization folded in.
// ---------------------------------------------------------------------------
__global__ __launch_bounds__(256) void k_rht_in(
    const float* __restrict__ x, const float* __restrict__ SV,
    unsigned short* __restrict__ out) {
    __shared__ float lds[4352];  // f(n) = n + (n>>4), max 4350
    int row = blockIdx.x;
    int t = threadIdx.x;
    const float* xr = x + (size_t)row * N_DIM;
    float v[16];
    // phase A: n = t + 256r
#pragma unroll
    for (int r = 0; r < 16; r++) {
        int n = t + (r << 8);
        v[r] = xr[n] * SV[n] * 0.015625f;
    }
    h16(v);
#pragma unroll
    for (int r = 0; r < 16; r++) { int n = t + (r << 8); lds[n + (n >> 4)] = v[r]; }
    __syncthreads();
    // phase B: n = 16t + r
#pragma unroll
    for (int r = 0; r < 16; r++) { int n = (t << 4) + r; v[r] = lds[n + (n >> 4)]; }
    h16(v);
#pragma unroll
    for (int r = 0; r < 16; r++) { int n = (t << 4) + r; lds[n + (n >> 4)] = v[r]; }
    __syncthreads();
    // phase C: n = (t&15) | (r<<4) | ((t>>4)<<8)
#pragma unroll
    for (int r = 0; r < 16; r++) {
        int n = (t & 15) | (r << 4) | ((t >> 4) << 8);
        v[r] = lds[n + (n >> 4)];
    }
    h16(v);
#pragma unroll
    for (int r = 0; r < 16; r++) {
        int n = (t & 15) | (r << 4) | ((t >> 4) << 8);
        lds[n + (n >> 4)] = v[r];
    }
    __syncthreads();
    unsigned short* orow = out + (size_t)row * N_DIM;
#pragma unroll
    for (int r = 0; r < 16; r++) {
        int n = t + (r << 8);
        orow[n] = f2bf(lds[n + (n >> 4)]);
    }
}

// ---------------------------------------------------------------------------
// Kernel 3: y[b,m] = SU[m] * dot(x_rht[b,:], W''[m,:])   (NT GEMM)
// m97 structure: 128x128x32 tile, 4 waves x (4x4 of 16x16x32 bf16 MFMA),
// global_load_lds width 16, 2-barrier K-loop. f32 output to d_out.
// ---------------------------------------------------------------------------
__global__ __launch_bounds__(256) void k_gemm(
    const unsigned short* __restrict__ A,   // (B_DIM, N_DIM) bf16
    const unsigned short* __restrict__ Bw,  // (M_DIM, N_DIM) bf16  (= W'')
    const float* __restrict__ SU,
    float* __restrict__ C) {                // (B_DIM, M_DIM) f32
    __shared__ __align__(16) unsigned short As[128 * 32];
    __shared__ __align__(16) unsigned short Bs[128 * 32];
    int t = threadIdx.x;
    int w = t >> 6;
    int l = t & 63;
    int bn = blockIdx.x;  // M tile
    int bm = blockIdx.y;  // B tile

    // staging: wave w covers rows [w*32, w*32+32); lane l -> row l>>2, 16B chunk l&3
    int srow = w * 32 + (l >> 2);
    int scol = (l & 3) * 8;
    const unsigned short* ga0 = A + (size_t)(bm * 128 + srow) * N_DIM + scol;
    const unsigned short* ga1 = ga0 + (size_t)16 * N_DIM;
    const unsigned short* gb0 = Bw + (size_t)(bn * 128 + srow) * N_DIM + scol;
    const unsigned short* gb1 = gb0 + (size_t)16 * N_DIM;
    // wave-uniform LDS bases; HW scatters lane l at base + l*16B, which equals
    // row (w*32 + l>>2), chunk (l&3) in the unpadded 32-elem-row layout.
    unsigned short* la0 = &As[(w * 32) * 32];
    unsigned short* la1 = &As[(w * 32 + 16) * 32];
    unsigned short* lb0 = &Bs[(w * 32) * 32];
    unsigned short* lb1 = &Bs[(w * 32 + 16) * 32];

    int wm = (w & 1) << 6;  // wave quadrant
    int wn = (w >> 1) << 6;
    int quad = l >> 4;
    int ln = l & 15;

    // MFMA fragment pointers: A[m=lane&15][k=quad*8+j]  (m91-verified layout)
    const unsigned short* arp[4];
    const unsigned short* brp[4];
#pragma unroll
    for (int i = 0; i < 4; i++) arp[i] = &As[(wm + i * 16 + ln) * 32 + quad * 8];
#pragma unroll
    for (int j = 0; j < 4; j++) brp[j] = &Bs[(wn + j * 16 + ln) * 32 + quad * 8];

    f32x4 acc[4][4];
#pragma unroll
    for (int i = 0; i < 4; i++)
#pragma unroll
        for (int j = 0; j < 4; j++) {
            f32x4 z = {0.f, 0.f, 0.f, 0.f};
            acc[i][j] = z;
        }

    for (int kk = 0; kk < N_DIM / 32; kk++) {
        load_lds16(ga0, la0);
        load_lds16(ga1, la1);
        load_lds16(gb0, lb0);
        load_lds16(gb1, lb1);
        ga0 += 32; ga1 += 32; gb0 += 32; gb1 += 32;
        __syncthreads();  // vmcnt(0) drain before barrier -> LDS ready
        bf16x8 af[4], bfr[4];
#pragma unroll
        for (int i = 0; i < 4; i++) af[i] = *(const bf16x8*)arp[i];
#pragma unroll
        for (int j = 0; j < 4; j++) bfr[j] = *(const bf16x8*)brp[j];
#pragma unroll
        for (int i = 0; i < 4; i++)
#pragma unroll
            for (int j = 0; j < 4; j++)
                acc[i][j] = __builtin_amdgcn_mfma_f32_16x16x32_bf16(
                    af[i], bfr[j], acc[i][j], 0, 0, 0);
        __syncthreads();  // protect LDS from next iteration's staging
    }

    // epilogue: C/D layout col=lane&15, row=quad*4+reg  (m89/m91-verified)
#pragma unroll
    for (int j = 0; j < 4; j++) {
        int col = bn * 128 + wn + j * 16 + ln;
        float su = SU[col];
#pragma unroll
        for (int i = 0; i < 4; i++) {
#pragma unroll
            for (int r = 0; r < 4; r++) {
                int rowg = bm * 128 + wm + i * 16 + quad * 4 + r;
                C[(size_t)rowg * M_DIM + col] = acc[i][j][r] * su;
            }
        }
    }
}

extern "C" void kernel_launch(void* const* d_in, const int* in_sizes, int n_in,
                              void* d_out, int out_size, void* d_ws, size_t ws_size,
                              hipStream_t stream) {
    const float* x    = (const float*)d_in[0];
    const int*   q1   = (const int*)d_in[1];
    const int*   q2   = (const int*)d_in[2];
    const float* SU   = (const float*)d_in[3];
    const float* SV   = (const float*)d_in[4];
    const float* cb1  = (const float*)d_in[5];
    const float* cb2  = (const float*)d_in[6];
    const float* wsp  = (const float*)d_in[7];
    const float* irsp = (const float*)d_in[8];
    float* out = (float*)d_out;  // reference output dtype: float32

    // workspace: x_rht bf16 (64MiB) | W bf16 (32MiB)  => 96MiB total
    unsigned short* xrht = (unsigned short*)d_ws;
    unsigned short* Wb   = xrht + (size_t)B_DIM * N_DIM;

    k_build_w<<<dim3((M_DIM * G_DIM) / 256), dim3(256), 0, stream>>>(
        q1, q2, cb1, cb2, wsp, irsp, Wb);
    // W'' = (1/64) H_4096 W  (column-direction Hadamard, two H64 passes)
    k_hadw<<<dim3(N_DIM / 256, 64), dim3(256), 0, stream>>>(Wb, 1, 64, 1.0f);
    k_hadw<<<dim3(N_DIM / 256, 64), dim3(256), 0, stream>>>(Wb, 64, 1, 0.015625f);
    k_rht_in<<<dim3(B_DIM), dim3(256), 0, stream>>>(x, SV, xrht);
    k_gemm<<<dim3(M_DIM / 128, B_DIM / 128), dim3(256), 0, stream>>>(
        xrht, Wb, SU, out);
}